// Round 7
// baseline (180.696 us; speedup 1.0000x reference)
//
#include <hip/hip_runtime.h>
#include <hip/hip_bf16.h>

typedef __attribute__((ext_vector_type(8))) short bf16x8;
typedef __attribute__((ext_vector_type(4))) float f32x4;
typedef unsigned short u16;
typedef unsigned int u32;

__device__ __forceinline__ u16 f2bf(float f) {
    u32 u = __float_as_uint(f);
    u = (u + 0x7FFFu + ((u >> 16) & 1u)) >> 16;
    return (u16)u;
}
__device__ __forceinline__ u32 pk2(float a, float b) {
    return (u32)f2bf(a) | ((u32)f2bf(b) << 16);
}

#define GLDS16(g, l) __builtin_amdgcn_global_load_lds( \
    (const __attribute__((address_space(1))) u32*)(g), \
    (__attribute__((address_space(3))) u32*)(l), 16, 0, 0)

// counted-vmcnt barrier: loads beyond N stay in flight across the barrier (T3/T4)
#define BAR_CNT6() do { asm volatile("s_waitcnt vmcnt(6) lgkmcnt(0)" ::: "memory"); \
    __builtin_amdgcn_sched_barrier(0); __builtin_amdgcn_s_barrier(); } while (0)
#define BAR_CNT0() do { asm volatile("s_waitcnt vmcnt(0) lgkmcnt(0)" ::: "memory"); \
    __builtin_amdgcn_sched_barrier(0); __builtin_amdgcn_s_barrier(); } while (0)

// ---------- centers: cn = c/||c|| bf16, granule layout [b][kb24][dc4][k256][8] ----------
__global__ __launch_bounds__(256) void k_centers(const float* __restrict__ c, u16* __restrict__ cn) {
    int bid = blockIdx.x;                      // 512 blocks, 4 rows each
    int w = threadIdx.x >> 6, lane = threadIdx.x & 63;
    int row = (bid << 2) + w;                  // b*256 + k
    int b = row >> 8;
    __shared__ u16 rb[4][800];
    const float* src = c + (size_t)row * 768;
    float v[12]; float ss = 0.f;
#pragma unroll
    for (int j = 0; j < 12; ++j) { v[j] = src[lane + (j << 6)]; ss += v[j] * v[j]; }
#pragma unroll
    for (int m = 1; m < 64; m <<= 1) ss += __shfl_xor(ss, m, 64);
    float inv = 1.0f / sqrtf(ss);
#pragma unroll
    for (int j = 0; j < 12; ++j) rb[w][lane + (j << 6)] = f2bf(v[j] * inv);
    __syncthreads();
    int t = threadIdx.x;
    int k0 = (bid << 2) & 255;
#pragma unroll
    for (int p = 0; p < 2; ++p) {
        int idx = (p << 8) + t;
        if (idx < 384) {
            int g = idx >> 2, kr = idx & 3;
            uint4 val = *reinterpret_cast<const uint4*>(&rb[kr][g << 3]);
            int kb = g >> 2, dc = g & 3;
            size_t o = ((((size_t)(b * 24 + kb) << 2) + dc) << 8) + k0 + kr;
            *reinterpret_cast<uint4*>(cn + (o << 3)) = val;
        }
    }
}

// ---------- GEMM1: 256tok x 256K, 8 waves, 3-buffer counted-vmcnt pipeline ----------
__global__ __launch_bounds__(512, 2) void k_gemm1(const float* __restrict__ x, const u16* __restrict__ cn,
                                                  u16* __restrict__ probT, float* __restrict__ den) {
    const int b = blockIdx.y;
    const int n0 = blockIdx.x << 8;            // 256-token tile
    const int t = threadIdx.x;
    const int wave = t >> 6, lane = t & 63;
    const int lg = lane >> 4, lr = lane & 15;
    const int wm = wave >> 1, wk = wave & 1;
    const int tok0 = wm << 6;                  // wave token base (0/64/128/192)
    const int kb0 = wk << 7;                   // wave K base (0/128)

    __shared__ union {
        struct {
            u16 A[3][4][258][8];               // 49536 B; dc-plane stride 4128B (=8 mod 32 dw)
            u16 B[3][4][256][8];               // 49152 B; GLDS-linear granules
        } s;
        u16 T[256][264];                       // 135168 B transpose staging
    } u;
    __shared__ float inv_s[256];
    __shared__ float ksum[2][256];
    __shared__ float denp[256];

    if (t < 256) denp[t] = 0.f;

    f32x4 acc[8][4];
#pragma unroll
    for (int kf = 0; kf < 8; ++kf)
#pragma unroll
        for (int tf = 0; tf < 4; ++tf) acc[kf][tf] = (f32x4){0.f, 0.f, 0.f, 0.f};

    const char* cnb = (const char*)(cn + (size_t)b * 24 * 4 * 256 * 8);
    const int tokS = t >> 1;                   // 0..255
    const int dcS = t & 1;                     // d-halves (16 d each)
    const float* ap = x + ((size_t)b * 8192 + n0 + tokS) * 768 + (dcS << 4);

    float sq = 0.f;
    float4 fE[4], fO[4];                       // ping-pong A-load register sets (static names)

    auto issueA = [&](int kb, float4* f) {
        const float* p = ap + (kb << 5);
        f[0] = *reinterpret_cast<const float4*>(p);
        f[1] = *reinterpret_cast<const float4*>(p + 4);
        f[2] = *reinterpret_cast<const float4*>(p + 8);
        f[3] = *reinterpret_cast<const float4*>(p + 12);
    };
    auto writeA = [&](int buf, float4* f) {
#pragma unroll
        for (int j = 0; j < 4; ++j)
            sq += f[j].x * f[j].x + f[j].y * f[j].y + f[j].z * f[j].z + f[j].w * f[j].w;
        *reinterpret_cast<uint4*>(&u.s.A[buf][(dcS << 1) + 0][tokS][0]) =
            make_uint4(pk2(f[0].x, f[0].y), pk2(f[0].z, f[0].w), pk2(f[1].x, f[1].y), pk2(f[1].z, f[1].w));
        *reinterpret_cast<uint4*>(&u.s.A[buf][(dcS << 1) + 1][tokS][0]) =
            make_uint4(pk2(f[2].x, f[2].y), pk2(f[2].z, f[2].w), pk2(f[3].x, f[3].y), pk2(f[3].z, f[3].w));
    };
    auto issueB = [&](int buf, int kb) {
        const char* src = cnb + (size_t)kb * 16384 + (wave << 11) + (lane << 4);
        char* dst = (char*)&u.s.B[buf][0][0][0] + (wave << 11);
        GLDS16(src, dst);
        GLDS16(src + 1024, dst + 1024);
    };
    auto mfmaStep = [&](int buf) {
        bf16x8 a[4];
#pragma unroll
        for (int tf = 0; tf < 4; ++tf)
            a[tf] = *reinterpret_cast<const bf16x8*>(&u.s.A[buf][lg][tok0 + (tf << 4) + lr][0]);
#pragma unroll
        for (int kf = 0; kf < 8; ++kf) {
            bf16x8 bb = *reinterpret_cast<const bf16x8*>(&u.s.B[buf][lg][kb0 + (kf << 4) + lr][0]);
#pragma unroll
            for (int tf = 0; tf < 4; ++tf)
                acc[kf][tf] = __builtin_amdgcn_mfma_f32_16x16x32_bf16(a[tf], bb, acc[kf][tf], 0, 0, 0);
        }
    };

    // prologue: 2 iterations in flight before first barrier
    issueA(0, fE); issueB(0, 0);
    issueA(1, fO); issueB(1, 1);
    writeA(0, fE);
    BAR_CNT6();

    // 24 K-steps, manually 2-unrolled for the fE/fO ping-pong
    for (int kb = 0; kb < 24; kb += 2) {
        int bi0 = kb % 3, bi1 = (kb + 1) % 3, bi2 = (kb + 2) % 3;
        // sub-iter kb (even -> fE holds A(kb+2) after issue, fO holds A(kb+1))
        if (kb < 22) { issueA(kb + 2, fE); issueB(bi2, kb + 2); }
        mfmaStep(bi0);
        writeA(bi1, fO);
        BAR_CNT6();
        // sub-iter kb+1
        if (kb < 21) { issueA(kb + 3, fO); issueB(bi0, kb + 3); }
        mfmaStep(bi1);
        if (kb < 22) {
            writeA(bi2, fE);
            if (kb == 20) { BAR_CNT0(); } else { BAR_CNT6(); }
        }
    }
    // last sub-iter (kb=23) computed in final trip; nothing outstanding now

    // inverse norms (partner t^1 holds the complementary 16 d per token)
    sq += __shfl_xor(sq, 1, 64);
    if ((t & 1) == 0) inv_s[tokS] = 1.0f / sqrtf(sq);
    __syncthreads();

    float iv[4][4];
#pragma unroll
    for (int tf = 0; tf < 4; ++tf)
#pragma unroll
        for (int r = 0; r < 4; ++r)
            iv[tf][r] = inv_s[tok0 + (tf << 4) + (lg << 2) + r];

    // exp (bounded logits, no max-subtract) + per-token partial sums over this wave's 128 K
    float rowsum[4][4];
#pragma unroll
    for (int tf = 0; tf < 4; ++tf)
#pragma unroll
        for (int r = 0; r < 4; ++r) rowsum[tf][r] = 0.f;
#pragma unroll
    for (int kf = 0; kf < 8; ++kf)
#pragma unroll
        for (int tf = 0; tf < 4; ++tf)
#pragma unroll
            for (int r = 0; r < 4; ++r) {
                float e = __expf(acc[kf][tf][r] * iv[tf][r]);
                acc[kf][tf][r] = e; rowsum[tf][r] += e;
            }
#pragma unroll
    for (int tf = 0; tf < 4; ++tf)
#pragma unroll
        for (int r = 0; r < 4; ++r) {
#pragma unroll
            for (int m = 1; m < 16; m <<= 1) rowsum[tf][r] += __shfl_xor(rowsum[tf][r], m, 64);
        }
    if (lr == 0) {
#pragma unroll
        for (int tf = 0; tf < 4; ++tf)
#pragma unroll
            for (int r = 0; r < 4; ++r)
                ksum[wk][tok0 + (tf << 4) + (lg << 2) + r] = rowsum[tf][r];
    }
    __syncthreads();

    float rs[4][4];
#pragma unroll
    for (int tf = 0; tf < 4; ++tf)
#pragma unroll
        for (int r = 0; r < 4; ++r) {
            int idx = tok0 + (tf << 4) + (lg << 2) + r;
            rs[tf][r] = 1.0f / (ksum[0][idx] + ksum[1][idx]);
        }

    // prob, den column sums, transpose into LDS T[K][token]
    float dcol[8];
#pragma unroll
    for (int kf = 0; kf < 8; ++kf) dcol[kf] = 0.f;
#pragma unroll
    for (int kf = 0; kf < 8; ++kf)
#pragma unroll
        for (int tf = 0; tf < 4; ++tf)
#pragma unroll
            for (int r = 0; r < 4; ++r) {
                float p = acc[kf][tf][r] * rs[tf][r];
                acc[kf][tf][r] = p; dcol[kf] += p;
            }
#pragma unroll
    for (int kf = 0; kf < 8; ++kf) {
        dcol[kf] += __shfl_xor(dcol[kf], 16, 64);
        dcol[kf] += __shfl_xor(dcol[kf], 32, 64);
    }
    if (lg == 0) {
#pragma unroll
        for (int kf = 0; kf < 8; ++kf) atomicAdd(&denp[kb0 + (kf << 4) + lr], dcol[kf]);
    }
#pragma unroll
    for (int kf = 0; kf < 8; ++kf)
#pragma unroll
        for (int tf = 0; tf < 4; ++tf)
            *reinterpret_cast<ushort4*>(&u.T[kb0 + (kf << 4) + lr][tok0 + (tf << 4) + (lg << 2)]) =
                make_ushort4(f2bf(acc[kf][tf][0]), f2bf(acc[kf][tf][1]),
                             f2bf(acc[kf][tf][2]), f2bf(acc[kf][tf][3]));
    __syncthreads();

    // coalesced writeout of probT tile [256][256]
    u16* pTb = probT + (size_t)b * 256 * 8192 + n0;
#pragma unroll
    for (int i = 0; i < 16; ++i) {
        int idx = (i << 9) + t;
        int row = idx >> 5, ch = idx & 31;
        *reinterpret_cast<uint4*>(pTb + (size_t)row * 8192 + (ch << 3)) =
            *reinterpret_cast<const uint4*>(&u.T[row][ch << 3]);
    }
    if (t < 256) atomicAdd(&den[(b << 8) + t], denp[t]);
}

// ---------- GEMM2 (R2-proven body + XCD grouping): num_part[s][b][k][d] ----------
__global__ __launch_bounds__(256) void k_gemm2(const float* __restrict__ x, const u16* __restrict__ probT,
                                               float* __restrict__ num_part) {
    const int bid = blockIdx.x;                // 768 blocks
    const int xcd = bid & 7, slot = bid >> 3;
    const int orig = xcd * 96 + slot;
    const int dt = orig % 12, sb = orig / 12;  // 12 d-tiles of one (s,b) share an XCD
    const int s = sb >> 3, b = sb & 7;
    const int d0 = dt << 6;
    const int t = threadIdx.x;
    const int wave = t >> 6, lane = t & 63;
    const int lg = lane >> 4, lr = lane & 15;

    f32x4 acc[4][4];
#pragma unroll
    for (int m = 0; m < 4; ++m)
#pragma unroll
        for (int tt = 0; tt < 4; ++tt) acc[m][tt] = (f32x4){0.f, 0.f, 0.f, 0.f};

    const int n0 = s << 10;
    const u16* pA = probT + (size_t)b * 256 * 8192;
    const float* xB = x + (size_t)b * 8192 * 768;

    for (int kb = 0; kb < 32; ++kb) {
        int nbase = n0 + (kb << 5);
        bf16x8 a[4];
#pragma unroll
        for (int m = 0; m < 4; ++m) {
            int k = (wave << 6) + (m << 4) + lr;
            a[m] = *reinterpret_cast<const bf16x8*>(pA + (size_t)k * 8192 + nbase + (lg << 3));
        }
        const float* xr = xB + (size_t)(nbase + (lg << 3)) * 768 + d0 + lr;
        bf16x8 bb[4];
#pragma unroll
        for (int tt = 0; tt < 4; ++tt)
#pragma unroll
            for (int j = 0; j < 8; ++j) {
                float f = xr[(size_t)j * 768 + (tt << 4)];
                bb[tt][j] = (short)f2bf(f);
            }
#pragma unroll
        for (int m = 0; m < 4; ++m)
#pragma unroll
            for (int tt = 0; tt < 4; ++tt)
                acc[m][tt] = __builtin_amdgcn_mfma_f32_16x16x32_bf16(a[m], bb[tt], acc[m][tt], 0, 0, 0);
    }

    float* np = num_part + ((size_t)s * 8 + b) * 256 * 768;
#pragma unroll
    for (int m = 0; m < 4; ++m) {
        int kb_ = (wave << 6) + (m << 4) + (lg << 2);
#pragma unroll
        for (int reg = 0; reg < 4; ++reg)
#pragma unroll
            for (int tt = 0; tt < 4; ++tt)
                np[(size_t)(kb_ + reg) * 768 + d0 + (tt << 4) + lr] = acc[m][tt][reg];
    }
}

// ---------- finalize: out = sum_s num_part / (den + eps) ----------
__global__ __launch_bounds__(256) void k_final(const float* __restrict__ num_part, const float* __restrict__ den,
                                               float* __restrict__ out) {
    int i = blockIdx.x * 256 + threadIdx.x;
    float sum = 0.f;
#pragma unroll
    for (int ss = 0; ss < 8; ++ss) sum += num_part[(size_t)ss * 1572864 + i];
    out[i] = sum / (den[i / 768] + 1e-8f);
}

extern "C" void kernel_launch(void* const* d_in, const int* in_sizes, int n_in,
                              void* d_out, int out_size, void* d_ws, size_t ws_size,
                              hipStream_t stream) {
    const float* x = (const float*)d_in[0];
    const float* centers = (const float*)d_in[1];
    float* out = (float*)d_out;
    char* ws = (char*)d_ws;
    u16* cn       = (u16*)ws;                    //  3,145,728 B
    u16* probT    = (u16*)(ws + 3145728);        // 33,554,432 B
    float* den    = (float*)(ws + 36700160);     //      8,192 B
    float* numpt  = (float*)(ws + 36708352);     // 50,331,648 B  (total ~87 MB)

    hipMemsetAsync(den, 0, 8192, stream);
    k_centers<<<512, 256, 0, stream>>>(centers, cn);
    k_gemm1<<<dim3(32, 8), 512, 0, stream>>>(x, cn, probT, den);
    k_gemm2<<<768, 256, 0, stream>>>(x, probT, numpt);
    k_final<<<6144, 256, 0, stream>>>(numpt, den, out);
}